// Round 8
// baseline (445.061 us; speedup 1.0000x reference)
//
#include <hip/hip_runtime.h>
#include <cmath>

constexpr unsigned HASH_SIZE = 1u << 19;
constexpr unsigned HASH_MASK = HASH_SIZE - 1u;
constexpr unsigned P2 = 2654435761u;
constexpr unsigned P3 = 805459861u;
constexpr int NKEYS = 65536;
constexpr int NSHARD = 8;

struct ResArr { float r[16]; };
typedef float f4 __attribute__((ext_vector_type(4)));

// ---------------- stage 1: per-block min/max partials (no atomics) ----------
__global__ __launch_bounds__(256) void he_minmax1(const float* __restrict__ x, int n,
                                                  float* __restrict__ part) {
    int tid = blockIdx.x * blockDim.x + threadIdx.x;
    int stride = gridDim.x * blockDim.x;
    float mn0 = INFINITY, mn1 = INFINITY, mn2 = INFINITY;
    float mx0 = -INFINITY, mx1 = -INFINITY, mx2 = -INFINITY;
    for (int i = tid; i < n; i += stride) {
        float a = x[3 * i + 0];
        float b = x[3 * i + 1];
        float c = x[3 * i + 2];
        mn0 = fminf(mn0, a); mx0 = fmaxf(mx0, a);
        mn1 = fminf(mn1, b); mx1 = fmaxf(mx1, b);
        mn2 = fminf(mn2, c); mx2 = fmaxf(mx2, c);
    }
    #pragma unroll
    for (int off = 32; off > 0; off >>= 1) {
        mn0 = fminf(mn0, __shfl_down(mn0, off));
        mn1 = fminf(mn1, __shfl_down(mn1, off));
        mn2 = fminf(mn2, __shfl_down(mn2, off));
        mx0 = fmaxf(mx0, __shfl_down(mx0, off));
        mx1 = fmaxf(mx1, __shfl_down(mx1, off));
        mx2 = fmaxf(mx2, __shfl_down(mx2, off));
    }
    __shared__ float s[6][4];
    int w = threadIdx.x >> 6;
    if ((threadIdx.x & 63) == 0) {
        s[0][w] = mn0; s[1][w] = mn1; s[2][w] = mn2;
        s[3][w] = mx0; s[4][w] = mx1; s[5][w] = mx2;
    }
    __syncthreads();
    if (threadIdx.x == 0) {
        float* p = part + 6 * blockIdx.x;
        p[0] = fminf(fminf(s[0][0], s[0][1]), fminf(s[0][2], s[0][3]));
        p[1] = fminf(fminf(s[1][0], s[1][1]), fminf(s[1][2], s[1][3]));
        p[2] = fminf(fminf(s[2][0], s[2][1]), fminf(s[2][2], s[2][3]));
        p[3] = fmaxf(fmaxf(s[3][0], s[3][1]), fmaxf(s[3][2], s[3][3]));
        p[4] = fmaxf(fmaxf(s[4][0], s[4][1]), fmaxf(s[4][2], s[4][3]));
        p[5] = fmaxf(fmaxf(s[5][0], s[5][1]), fmaxf(s[5][2], s[5][3]));
    }
}

// ---------------- stage 2: combine 256 partials ----------------------------
__global__ __launch_bounds__(256) void he_minmax2(const float* __restrict__ part,
                                                  float* __restrict__ mm) {
    int t = threadIdx.x;
    const float* p = part + 6 * t;
    float mn0 = p[0], mn1 = p[1], mn2 = p[2];
    float mx0 = p[3], mx1 = p[4], mx2 = p[5];
    #pragma unroll
    for (int off = 32; off > 0; off >>= 1) {
        mn0 = fminf(mn0, __shfl_down(mn0, off));
        mn1 = fminf(mn1, __shfl_down(mn1, off));
        mn2 = fminf(mn2, __shfl_down(mn2, off));
        mx0 = fmaxf(mx0, __shfl_down(mx0, off));
        mx1 = fmaxf(mx1, __shfl_down(mx1, off));
        mx2 = fmaxf(mx2, __shfl_down(mx2, off));
    }
    __shared__ float s[6][4];
    int w = t >> 6;
    if ((t & 63) == 0) {
        s[0][w] = mn0; s[1][w] = mn1; s[2][w] = mn2;
        s[3][w] = mx0; s[4][w] = mx1; s[5][w] = mx2;
    }
    __syncthreads();
    if (t == 0) {
        mm[0] = fminf(fminf(s[0][0], s[0][1]), fminf(s[0][2], s[0][3]));
        mm[1] = fminf(fminf(s[1][0], s[1][1]), fminf(s[1][2], s[1][3]));
        mm[2] = fminf(fminf(s[2][0], s[2][1]), fminf(s[2][2], s[2][3]));
        mm[3] = fmaxf(fmaxf(s[3][0], s[3][1]), fmaxf(s[3][2], s[3][3]));
        mm[4] = fmaxf(fmaxf(s[4][0], s[4][1]), fmaxf(s[4][2], s[4][3]));
        mm[5] = fmaxf(fmaxf(s[5][0], s[5][1]), fmaxf(s[5][2], s[5][3]));
    }
}

// ---------------- sort passes ------------------------------------------------
__device__ __forceinline__ unsigned spread5(unsigned v) {
    return (v & 1u) | ((v & 2u) << 2) | ((v & 4u) << 4) | ((v & 8u) << 6) | ((v & 16u) << 8);
}

__device__ __forceinline__ unsigned morton_key(const float* __restrict__ x, int i,
                                               const float* __restrict__ mm) {
    float den0 = (mm[3] - mm[0]) + 1e-8f;
    float den1 = (mm[4] - mm[1]) + 1e-8f;
    float den2 = (mm[5] - mm[2]) + 1e-8f;
    float xs = (x[3 * i + 0] - mm[0]) / den0;
    float ys = (x[3 * i + 1] - mm[1]) / den1;
    float zs = (x[3 * i + 2] - mm[2]) / den2;
    unsigned kx = min(63u, (unsigned)(xs * 64.0f));
    unsigned ky = min(31u, (unsigned)(ys * 32.0f));
    unsigned kz = min(31u, (unsigned)(zs * 32.0f));
    return ((kx >> 5) << 15)
         | (spread5(kx & 31u) << 2)
         | (spread5(ky) << 1)
         | spread5(kz);
}

// histogram only (key recomputed later in scatter; saves keyA traffic)
__global__ __launch_bounds__(256) void he_hist(const float* __restrict__ x, int n,
                                               const float* __restrict__ mm,
                                               unsigned* __restrict__ planes) {
    int i = blockIdx.x * 256 + threadIdx.x;
    if (i >= n) return;
    unsigned key = morton_key(x, i, mm);
    atomicAdd(&planes[(i & (NSHARD - 1)) * NKEYS + key], 1u);
}

// fused: shard-exclusive prefix per key + block-local exclusive scan of key totals
__global__ __launch_bounds__(256) void he_scanSA(unsigned* __restrict__ planes,
                                                 unsigned* __restrict__ keytot,
                                                 unsigned* __restrict__ bsum) {
    int tid = threadIdx.x;
    int k = blockIdx.x * 256 + tid;
    unsigned c[NSHARD];
    #pragma unroll
    for (int s = 0; s < NSHARD; ++s) c[s] = planes[s * NKEYS + k];
    unsigned run = 0;
    #pragma unroll
    for (int s = 0; s < NSHARD; ++s) {
        planes[s * NKEYS + k] = run;
        run += c[s];
    }
    __shared__ unsigned sh[256];
    unsigned v = run;
    sh[tid] = v;
    __syncthreads();
    #pragma unroll
    for (int off = 1; off < 256; off <<= 1) {
        unsigned t = (tid >= off) ? sh[tid - off] : 0u;
        __syncthreads();
        sh[tid] += t;
        __syncthreads();
    }
    keytot[k] = sh[tid] - v;                 // exclusive within block
    if (tid == 255) bsum[blockIdx.x] = sh[255];
}

__global__ __launch_bounds__(256) void he_scanB(unsigned* __restrict__ bsum) {
    __shared__ unsigned s[256];
    int tid = threadIdx.x;
    unsigned v = bsum[tid];
    s[tid] = v;
    __syncthreads();
    #pragma unroll
    for (int off = 1; off < 256; off <<= 1) {
        unsigned t = (tid >= off) ? s[tid - off] : 0u;
        __syncthreads();
        s[tid] += t;
        __syncthreads();
    }
    bsum[tid] = s[tid] - v;
}

__global__ __launch_bounds__(256) void he_scanC(unsigned* __restrict__ planes,
                                                const unsigned* __restrict__ keytot,
                                                const unsigned* __restrict__ bsum) {
    int g = blockIdx.x * 256 + threadIdx.x;
    unsigned base = keytot[g] + bsum[blockIdx.x];
    #pragma unroll
    for (int s = 0; s < NSHARD; ++s) planes[s * NKEYS + g] += base;
}

// scatter scaled coords (+orig index) to sorted slot; key recomputed bit-identically
__global__ __launch_bounds__(256) void he_scatter(const float* __restrict__ x, int n,
                                                  const float* __restrict__ mm,
                                                  unsigned* __restrict__ planes,
                                                  f4* __restrict__ xsorted) {
    int i = blockIdx.x * 256 + threadIdx.x;
    if (i >= n) return;
    float den0 = (mm[3] - mm[0]) + 1e-8f;
    float den1 = (mm[4] - mm[1]) + 1e-8f;
    float den2 = (mm[5] - mm[2]) + 1e-8f;
    float xs = (x[3 * i + 0] - mm[0]) / den0;
    float ys = (x[3 * i + 1] - mm[1]) / den1;
    float zs = (x[3 * i + 2] - mm[2]) / den2;
    unsigned kx = min(63u, (unsigned)(xs * 64.0f));
    unsigned ky = min(31u, (unsigned)(ys * 32.0f));
    unsigned kz = min(31u, (unsigned)(zs * 32.0f));
    unsigned key = ((kx >> 5) << 15)
                 | (spread5(kx & 31u) << 2)
                 | (spread5(ky) << 1)
                 | spread5(kz);
    unsigned pos = atomicAdd(&planes[(i & (NSHARD - 1)) * NKEYS + key], 1u);
    f4 v;
    v.x = xs; v.y = ys; v.z = zs; v.w = __uint_as_float((unsigned)i);
    xsorted[pos] = v;
}

// ---------------- encode core: XOR-paired x0/x1 corner loads ----------------
// i100 = i000 ^ (cx^(cx+1)). For even cx the pair lives in one aligned 16B
// block -> one float4 load serves both corners (requests x0.75 at fine levels).
// Odd-cx lanes issue the second load exec-masked. Branchless selects keep
// VGPR low (r3's branchy variant hit 184 VGPR; this should stay ~48-64).
__device__ __forceinline__ void enc_core(float xs, float ys, float zs,
                                         const float* __restrict__ tables,
                                         const ResArr& res, float o[32]) {
    #pragma unroll
    for (int l = 0; l < 16; ++l) {
        float R = res.r[l];
        float xg = xs * R, yg = ys * R, zg = zs * R;
        float fx = floorf(xg), fy = floorf(yg), fz = floorf(zg);
        float tx = xg - fx, ty = yg - fy, tz = zg - fz;
        unsigned cx = (unsigned)fx, cy = (unsigned)fy, cz = (unsigned)fz;

        unsigned hy0 = cy * P2, hy1 = hy0 + P2;
        unsigned hz0 = cz * P3, hz1 = hz0 + P3;
        unsigned dx = cx ^ (cx + 1u);
        bool odd = (cx & 1u) != 0u;

        const float2* __restrict__ T = (const float2*)tables + (size_t)l * HASH_SIZE;

        float wx0 = 1.0f - tx, wx1 = tx;
        float wy0 = 1.0f - ty, wy1 = ty;
        float wz0 = 1.0f - tz, wz1 = tz;

        unsigned hyz0 = hy0 ^ hz0, hyz1 = hy1 ^ hz0, hyz2 = hy0 ^ hz1, hyz3 = hy1 ^ hz1;
        float wyz0 = wy0 * wz0, wyz1 = wy1 * wz0, wyz2 = wy0 * wz1, wyz3 = wy1 * wz1;

        float a0 = 0.0f, a1 = 0.0f;

        #define CORNER_PAIR(HYZ, WYZ)                                         \
        {                                                                     \
            unsigned ia = (cx ^ (HYZ)) & HASH_MASK;                           \
            f4 q = *(const f4*)(T + (ia & ~1u));                              \
            bool hi = (ia & 1u) != 0u;                                        \
            float fax = hi ? q.z : q.x;                                       \
            float fay = hi ? q.w : q.y;                                       \
            float fbx, fby;                                                   \
            if (odd) {                                                        \
                float2 fb = T[ia ^ dx];                                       \
                fbx = fb.x; fby = fb.y;                                       \
            } else {                                                          \
                fbx = hi ? q.x : q.z;                                         \
                fby = hi ? q.y : q.w;                                         \
            }                                                                 \
            float wA = wx0 * (WYZ);                                           \
            float wB = wx1 * (WYZ);                                           \
            a0 += wA * fax;  a1 += wA * fay;                                  \
            a0 += wB * fbx;  a1 += wB * fby;                                  \
        }

        CORNER_PAIR(hyz0, wyz0);
        CORNER_PAIR(hyz1, wyz1);
        CORNER_PAIR(hyz2, wyz2);
        CORNER_PAIR(hyz3, wyz3);
        #undef CORNER_PAIR

        o[2 * l + 0] = a0;
        o[2 * l + 1] = a1;
    }
}

__device__ __forceinline__ int swz_block(int b, int nwg) {
    int q = nwg >> 3, r = nwg & 7;
    int xcd = b & 7, kk = b >> 3;
    return (xcd < r ? xcd * (q + 1) : r * (q + 1) + (xcd - r) * q) + kk;
}

// sorted input -> direct scattered output, PLAIN full-line stores (r7: exact 125MB)
__global__ __launch_bounds__(256) void he_encode_scatter(const f4* __restrict__ xsorted,
                                                         const float* __restrict__ tables,
                                                         float* __restrict__ out, int n, ResArr res) {
    int sb = swz_block(blockIdx.x, gridDim.x);
    int j = sb * 256 + threadIdx.x;
    if (j >= n) return;
    f4 p = xsorted[j];
    int i = (int)__float_as_uint(p.w);
    float o[32];
    enc_core(p.x, p.y, p.z, tables, res, o);
    float* op = out + (size_t)i * 32;
    #pragma unroll
    for (int k = 0; k < 8; ++k) {
        f4 v;
        v.x = o[4 * k + 0]; v.y = o[4 * k + 1]; v.z = o[4 * k + 2]; v.w = o[4 * k + 3];
        *(f4*)(op + 4 * k) = v;
    }
}

// tier0 fallback: unsorted direct
__global__ __launch_bounds__(256) void he_encode_plain(const float* __restrict__ x,
                                                       const float* __restrict__ tables,
                                                       const float* __restrict__ mm,
                                                       float* __restrict__ out, int n, ResArr res) {
    int i = blockIdx.x * 256 + threadIdx.x;
    if (i >= n) return;
    float den0 = (mm[3] - mm[0]) + 1e-8f;
    float den1 = (mm[4] - mm[1]) + 1e-8f;
    float den2 = (mm[5] - mm[2]) + 1e-8f;
    float xs = (x[3 * i + 0] - mm[0]) / den0;
    float ys = (x[3 * i + 1] - mm[1]) / den1;
    float zs = (x[3 * i + 2] - mm[2]) / den2;
    float o[32];
    enc_core(xs, ys, zs, tables, res, o);
    float* op = out + (size_t)i * 32;
    #pragma unroll
    for (int k = 0; k < 8; ++k) {
        f4 v;
        v.x = o[4 * k + 0]; v.y = o[4 * k + 1]; v.z = o[4 * k + 2]; v.w = o[4 * k + 3];
        *(f4*)(op + 4 * k) = v;
    }
}

extern "C" void kernel_launch(void* const* d_in, const int* in_sizes, int n_in,
                              void* d_out, int out_size, void* d_ws, size_t ws_size,
                              hipStream_t stream) {
    const float* x = (const float*)d_in[0];
    const float* tables = (const float*)d_in[1];
    float* out = (float*)d_out;
    int n = in_sizes[0] / 3;

    char* w = (char*)d_ws;
    float*    mm      = (float*)w;                       // 24 B
    float*    part    = (float*)(w + 4096);              // 6 KB
    unsigned* bsum    = (unsigned*)(w + 16384);          // 1 KB
    unsigned* keytot  = (unsigned*)(w + 32768);          // 256 KB
    unsigned* planes  = (unsigned*)(w + 524288);         // 2 MB
    f4*       xsorted = (f4*)(w + 0x300000);             // 16 MB

    const size_t NEED1 = 0x300000 + (size_t)16777216;    // 19 MB
    int tier = (ws_size >= NEED1) ? 1 : 0;
    if (n > (1 << 20)) tier = 0;

    ResArr res;
    double growth = exp((log(512.0) - log(16.0)) / 15.0);
    for (int l = 0; l < 16; ++l) {
        res.r[l] = (float)(int)(16.0 * pow(growth, (double)l));
    }

    int blocks = (n + 255) / 256;

    he_minmax1<<<256, 256, 0, stream>>>(x, n, part);
    he_minmax2<<<1, 256, 0, stream>>>(part, mm);

    if (tier >= 1) {
        hipMemsetAsync(planes, 0, (size_t)NSHARD * NKEYS * 4, stream);
        he_hist<<<blocks, 256, 0, stream>>>(x, n, mm, planes);
        he_scanSA<<<NKEYS / 256, 256, 0, stream>>>(planes, keytot, bsum);
        he_scanB<<<1, 256, 0, stream>>>(bsum);
        he_scanC<<<NKEYS / 256, 256, 0, stream>>>(planes, keytot, bsum);
        he_scatter<<<blocks, 256, 0, stream>>>(x, n, mm, planes, xsorted);
        he_encode_scatter<<<blocks, 256, 0, stream>>>(xsorted, tables, out, n, res);
    } else {
        he_encode_plain<<<blocks, 256, 0, stream>>>(x, tables, mm, out, n, res);
    }
}

// Round 9
// 318.859 us; speedup vs baseline: 1.3958x; 1.3958x over previous
//
#include <hip/hip_runtime.h>
#include <cmath>

constexpr unsigned HASH_SIZE = 1u << 19;
constexpr unsigned HASH_MASK = HASH_SIZE - 1u;
constexpr unsigned P2 = 2654435761u;
constexpr unsigned P3 = 805459861u;
constexpr int NKEYS = 65536;
constexpr int NSHARD = 8;

struct ResArr { float r[16]; };
typedef float f4 __attribute__((ext_vector_type(4)));

__device__ __forceinline__ unsigned spread5(unsigned v) {
    return (v & 1u) | ((v & 2u) << 2) | ((v & 4u) << 4) | ((v & 8u) << 6) | ((v & 16u) << 8);
}

// Fixed data-independent sort grid: only locality depends on it, never
// correctness, so no min/max needed (inputs ~N(0,1); outliers clamp).
__device__ __forceinline__ unsigned fixed_key(float a, float b, float c) {
    unsigned kx = (unsigned)min(63.0f, fmaxf(0.0f, (a + 5.2f) * 6.15f));
    unsigned ky = (unsigned)min(31.0f, fmaxf(0.0f, (b + 5.2f) * 3.07f));
    unsigned kz = (unsigned)min(31.0f, fmaxf(0.0f, (c + 5.2f) * 3.07f));
    return ((kx >> 5) << 15)
         | (spread5(kx & 31u) << 2)
         | (spread5(ky) << 1)
         | spread5(kz);
}

// ---------------- fused: min/max partials + sort histogram ------------------
__global__ __launch_bounds__(256) void he_minmax_hist(const float* __restrict__ x, int n,
                                                      float* __restrict__ part,
                                                      unsigned* __restrict__ planes) {
    int tid = blockIdx.x * blockDim.x + threadIdx.x;
    int stride = gridDim.x * blockDim.x;
    float mn0 = INFINITY, mn1 = INFINITY, mn2 = INFINITY;
    float mx0 = -INFINITY, mx1 = -INFINITY, mx2 = -INFINITY;
    for (int i = tid; i < n; i += stride) {
        float a = x[3 * i + 0];
        float b = x[3 * i + 1];
        float c = x[3 * i + 2];
        mn0 = fminf(mn0, a); mx0 = fmaxf(mx0, a);
        mn1 = fminf(mn1, b); mx1 = fmaxf(mx1, b);
        mn2 = fminf(mn2, c); mx2 = fmaxf(mx2, c);
        unsigned key = fixed_key(a, b, c);
        atomicAdd(&planes[(i & (NSHARD - 1)) * NKEYS + key], 1u);
    }
    #pragma unroll
    for (int off = 32; off > 0; off >>= 1) {
        mn0 = fminf(mn0, __shfl_down(mn0, off));
        mn1 = fminf(mn1, __shfl_down(mn1, off));
        mn2 = fminf(mn2, __shfl_down(mn2, off));
        mx0 = fmaxf(mx0, __shfl_down(mx0, off));
        mx1 = fmaxf(mx1, __shfl_down(mx1, off));
        mx2 = fmaxf(mx2, __shfl_down(mx2, off));
    }
    __shared__ float s[6][4];
    int w = threadIdx.x >> 6;
    if ((threadIdx.x & 63) == 0) {
        s[0][w] = mn0; s[1][w] = mn1; s[2][w] = mn2;
        s[3][w] = mx0; s[4][w] = mx1; s[5][w] = mx2;
    }
    __syncthreads();
    if (threadIdx.x == 0) {
        float* p = part + 6 * blockIdx.x;
        p[0] = fminf(fminf(s[0][0], s[0][1]), fminf(s[0][2], s[0][3]));
        p[1] = fminf(fminf(s[1][0], s[1][1]), fminf(s[1][2], s[1][3]));
        p[2] = fminf(fminf(s[2][0], s[2][1]), fminf(s[2][2], s[2][3]));
        p[3] = fmaxf(fmaxf(s[3][0], s[3][1]), fmaxf(s[3][2], s[3][3]));
        p[4] = fmaxf(fmaxf(s[4][0], s[4][1]), fmaxf(s[4][2], s[4][3]));
        p[5] = fmaxf(fmaxf(s[5][0], s[5][1]), fmaxf(s[5][2], s[5][3]));
    }
}

// fused: shard-exclusive prefix per key + block-local exclusive scan of key totals
__global__ __launch_bounds__(256) void he_scanSA(unsigned* __restrict__ planes,
                                                 unsigned* __restrict__ keytot,
                                                 unsigned* __restrict__ bsum) {
    int tid = threadIdx.x;
    int k = blockIdx.x * 256 + tid;
    unsigned c[NSHARD];
    #pragma unroll
    for (int s = 0; s < NSHARD; ++s) c[s] = planes[s * NKEYS + k];
    unsigned run = 0;
    #pragma unroll
    for (int s = 0; s < NSHARD; ++s) {
        planes[s * NKEYS + k] = run;
        run += c[s];
    }
    __shared__ unsigned sh[256];
    unsigned v = run;
    sh[tid] = v;
    __syncthreads();
    #pragma unroll
    for (int off = 1; off < 256; off <<= 1) {
        unsigned t = (tid >= off) ? sh[tid - off] : 0u;
        __syncthreads();
        sh[tid] += t;
        __syncthreads();
    }
    keytot[k] = sh[tid] - v;
    if (tid == 255) bsum[blockIdx.x] = sh[255];
}

// fused: scan of 256 block-sums + min/max combine (independent tiny jobs)
__global__ __launch_bounds__(256) void he_scanB_mm(unsigned* __restrict__ bsum,
                                                   const float* __restrict__ part,
                                                   float* __restrict__ mm) {
    int tid = threadIdx.x;
    __shared__ unsigned s[256];
    unsigned v = bsum[tid];
    s[tid] = v;
    __syncthreads();
    #pragma unroll
    for (int off = 1; off < 256; off <<= 1) {
        unsigned t = (tid >= off) ? s[tid - off] : 0u;
        __syncthreads();
        s[tid] += t;
        __syncthreads();
    }
    bsum[tid] = s[tid] - v;

    // min/max combine of 256 partials
    const float* p = part + 6 * tid;
    float mn0 = p[0], mn1 = p[1], mn2 = p[2];
    float mx0 = p[3], mx1 = p[4], mx2 = p[5];
    #pragma unroll
    for (int off = 32; off > 0; off >>= 1) {
        mn0 = fminf(mn0, __shfl_down(mn0, off));
        mn1 = fminf(mn1, __shfl_down(mn1, off));
        mn2 = fminf(mn2, __shfl_down(mn2, off));
        mx0 = fmaxf(mx0, __shfl_down(mx0, off));
        mx1 = fmaxf(mx1, __shfl_down(mx1, off));
        mx2 = fmaxf(mx2, __shfl_down(mx2, off));
    }
    __shared__ float sm[6][4];
    int w = tid >> 6;
    if ((tid & 63) == 0) {
        sm[0][w] = mn0; sm[1][w] = mn1; sm[2][w] = mn2;
        sm[3][w] = mx0; sm[4][w] = mx1; sm[5][w] = mx2;
    }
    __syncthreads();
    if (tid == 0) {
        mm[0] = fminf(fminf(sm[0][0], sm[0][1]), fminf(sm[0][2], sm[0][3]));
        mm[1] = fminf(fminf(sm[1][0], sm[1][1]), fminf(sm[1][2], sm[1][3]));
        mm[2] = fminf(fminf(sm[2][0], sm[2][1]), fminf(sm[2][2], sm[2][3]));
        mm[3] = fmaxf(fmaxf(sm[3][0], sm[3][1]), fmaxf(sm[3][2], sm[3][3]));
        mm[4] = fmaxf(fmaxf(sm[4][0], sm[4][1]), fmaxf(sm[4][2], sm[4][3]));
        mm[5] = fmaxf(fmaxf(sm[5][0], sm[5][1]), fmaxf(sm[5][2], sm[5][3]));
    }
}

__global__ __launch_bounds__(256) void he_scanC(unsigned* __restrict__ planes,
                                                const unsigned* __restrict__ keytot,
                                                const unsigned* __restrict__ bsum) {
    int g = blockIdx.x * 256 + threadIdx.x;
    unsigned base = keytot[g] + bsum[blockIdx.x];
    #pragma unroll
    for (int s = 0; s < NSHARD; ++s) planes[s * NKEYS + g] += base;
}

// scatter scaled coords (+orig index) to sorted slot; key recomputed from the
// same fixed grid (bit-identical to hist)
__global__ __launch_bounds__(256) void he_scatter(const float* __restrict__ x, int n,
                                                  const float* __restrict__ mm,
                                                  unsigned* __restrict__ planes,
                                                  f4* __restrict__ xsorted) {
    int i = blockIdx.x * 256 + threadIdx.x;
    if (i >= n) return;
    float a = x[3 * i + 0], b = x[3 * i + 1], c = x[3 * i + 2];
    float den0 = (mm[3] - mm[0]) + 1e-8f;
    float den1 = (mm[4] - mm[1]) + 1e-8f;
    float den2 = (mm[5] - mm[2]) + 1e-8f;
    float xs = (a - mm[0]) / den0;
    float ys = (b - mm[1]) / den1;
    float zs = (c - mm[2]) / den2;
    unsigned key = fixed_key(a, b, c);
    unsigned pos = atomicAdd(&planes[(i & (NSHARD - 1)) * NKEYS + key], 1u);
    f4 v;
    v.x = xs; v.y = ys; v.z = zs; v.w = __uint_as_float((unsigned)i);
    xsorted[pos] = v;
}

// ---------------- encode core: r7 version (8x float2; line-minimal) ---------
__device__ __forceinline__ void enc_core(float xs, float ys, float zs,
                                         const float* __restrict__ tables,
                                         const ResArr& res, float o[32]) {
    #pragma unroll
    for (int l = 0; l < 16; ++l) {
        float R = res.r[l];
        float xg = xs * R, yg = ys * R, zg = zs * R;
        float fx = floorf(xg), fy = floorf(yg), fz = floorf(zg);
        float tx = xg - fx, ty = yg - fy, tz = zg - fz;
        unsigned cx = (unsigned)fx, cy = (unsigned)fy, cz = (unsigned)fz;

        unsigned hx0 = cx,      hx1 = cx + 1u;
        unsigned hy0 = cy * P2, hy1 = hy0 + P2;
        unsigned hz0 = cz * P3, hz1 = hz0 + P3;

        const float2* __restrict__ T = (const float2*)tables + (size_t)l * HASH_SIZE;

        float2 f000 = T[(hx0 ^ hy0 ^ hz0) & HASH_MASK];
        float2 f100 = T[(hx1 ^ hy0 ^ hz0) & HASH_MASK];
        float2 f010 = T[(hx0 ^ hy1 ^ hz0) & HASH_MASK];
        float2 f110 = T[(hx1 ^ hy1 ^ hz0) & HASH_MASK];
        float2 f001 = T[(hx0 ^ hy0 ^ hz1) & HASH_MASK];
        float2 f101 = T[(hx1 ^ hy0 ^ hz1) & HASH_MASK];
        float2 f011 = T[(hx0 ^ hy1 ^ hz1) & HASH_MASK];
        float2 f111 = T[(hx1 ^ hy1 ^ hz1) & HASH_MASK];

        float wx0 = 1.0f - tx, wx1 = tx;
        float wy0 = 1.0f - ty, wy1 = ty;
        float wz0 = 1.0f - tz, wz1 = tz;

        float w000 = wx0 * wy0 * wz0;
        float w100 = wx1 * wy0 * wz0;
        float w010 = wx0 * wy1 * wz0;
        float w110 = wx1 * wy1 * wz0;
        float w001 = wx0 * wy0 * wz1;
        float w101 = wx1 * wy0 * wz1;
        float w011 = wx0 * wy1 * wz1;
        float w111 = wx1 * wy1 * wz1;

        float a0 = w000 * f000.x;
        float a1 = w000 * f000.y;
        a0 += w100 * f100.x;  a1 += w100 * f100.y;
        a0 += w010 * f010.x;  a1 += w010 * f010.y;
        a0 += w110 * f110.x;  a1 += w110 * f110.y;
        a0 += w001 * f001.x;  a1 += w001 * f001.y;
        a0 += w101 * f101.x;  a1 += w101 * f101.y;
        a0 += w011 * f011.x;  a1 += w011 * f011.y;
        a0 += w111 * f111.x;  a1 += w111 * f111.y;

        o[2 * l + 0] = a0;
        o[2 * l + 1] = a1;
    }
}

__device__ __forceinline__ int swz_block(int b, int nwg) {
    int q = nwg >> 3, r = nwg & 7;
    int xcd = b & 7, kk = b >> 3;
    return (xcd < r ? xcd * (q + 1) : r * (q + 1) + (xcd - r) * q) + kk;
}

// sorted input -> direct scattered output, PLAIN full-line stores
__global__ __launch_bounds__(256) void he_encode_scatter(const f4* __restrict__ xsorted,
                                                         const float* __restrict__ tables,
                                                         float* __restrict__ out, int n, ResArr res) {
    int sb = swz_block(blockIdx.x, gridDim.x);
    int j = sb * 256 + threadIdx.x;
    if (j >= n) return;
    f4 p = xsorted[j];
    int i = (int)__float_as_uint(p.w);
    float o[32];
    enc_core(p.x, p.y, p.z, tables, res, o);
    float* op = out + (size_t)i * 32;
    #pragma unroll
    for (int k = 0; k < 8; ++k) {
        f4 v;
        v.x = o[4 * k + 0]; v.y = o[4 * k + 1]; v.z = o[4 * k + 2]; v.w = o[4 * k + 3];
        *(f4*)(op + 4 * k) = v;
    }
}

// tier0 fallback: unsorted direct
__global__ __launch_bounds__(256) void he_encode_plain(const float* __restrict__ x,
                                                       const float* __restrict__ tables,
                                                       const float* __restrict__ mm,
                                                       float* __restrict__ out, int n, ResArr res) {
    int i = blockIdx.x * 256 + threadIdx.x;
    if (i >= n) return;
    float den0 = (mm[3] - mm[0]) + 1e-8f;
    float den1 = (mm[4] - mm[1]) + 1e-8f;
    float den2 = (mm[5] - mm[2]) + 1e-8f;
    float xs = (x[3 * i + 0] - mm[0]) / den0;
    float ys = (x[3 * i + 1] - mm[1]) / den1;
    float zs = (x[3 * i + 2] - mm[2]) / den2;
    float o[32];
    enc_core(xs, ys, zs, tables, res, o);
    float* op = out + (size_t)i * 32;
    #pragma unroll
    for (int k = 0; k < 8; ++k) {
        f4 v;
        v.x = o[4 * k + 0]; v.y = o[4 * k + 1]; v.z = o[4 * k + 2]; v.w = o[4 * k + 3];
        *(f4*)(op + 4 * k) = v;
    }
}

extern "C" void kernel_launch(void* const* d_in, const int* in_sizes, int n_in,
                              void* d_out, int out_size, void* d_ws, size_t ws_size,
                              hipStream_t stream) {
    const float* x = (const float*)d_in[0];
    const float* tables = (const float*)d_in[1];
    float* out = (float*)d_out;
    int n = in_sizes[0] / 3;

    char* w = (char*)d_ws;
    float*    mm      = (float*)w;                       // 24 B
    float*    part    = (float*)(w + 4096);              // 6 KB
    unsigned* bsum    = (unsigned*)(w + 16384);          // 1 KB
    unsigned* keytot  = (unsigned*)(w + 32768);          // 256 KB
    unsigned* planes  = (unsigned*)(w + 524288);         // 2 MB
    f4*       xsorted = (f4*)(w + 0x300000);             // 16 MB

    const size_t NEED1 = 0x300000 + (size_t)16777216;    // 19 MB
    int tier = (ws_size >= NEED1) ? 1 : 0;
    if (n > (1 << 20)) tier = 0;

    ResArr res;
    double growth = exp((log(512.0) - log(16.0)) / 15.0);
    for (int l = 0; l < 16; ++l) {
        res.r[l] = (float)(int)(16.0 * pow(growth, (double)l));
    }

    int blocks = (n + 255) / 256;

    if (tier >= 1) {
        hipMemsetAsync(planes, 0, (size_t)NSHARD * NKEYS * 4, stream);
        he_minmax_hist<<<256, 256, 0, stream>>>(x, n, part, planes);
        he_scanSA<<<NKEYS / 256, 256, 0, stream>>>(planes, keytot, bsum);
        he_scanB_mm<<<1, 256, 0, stream>>>(bsum, part, mm);
        he_scanC<<<NKEYS / 256, 256, 0, stream>>>(planes, keytot, bsum);
        he_scatter<<<blocks, 256, 0, stream>>>(x, n, mm, planes, xsorted);
        he_encode_scatter<<<blocks, 256, 0, stream>>>(xsorted, tables, out, n, res);
    } else {
        // fallback: original two-kernel minmax then direct encode
        he_minmax_hist<<<256, 256, 0, stream>>>(x, n, part, (unsigned*)(w + 524288));
        he_scanB_mm<<<1, 256, 0, stream>>>(bsum, part, mm);
        he_encode_plain<<<blocks, 256, 0, stream>>>(x, tables, mm, out, n, res);
    }
}